// Round 15
// baseline (1178.545 us; speedup 1.0000x reference)
//
#include <hip/hip_runtime.h>
#include <hip/hip_bf16.h>
#include <stdint.h>

// ConvIntrinsic: fused  out[k,o,t] = relu( Σ_f sw[t,f]·ms[k,f]
//                + Σ_{x,y,f} W3[o,t,x,y,f]·interp0[k,x,y,f] + bias[t] )
// => GEMM (K=100000 × 1312) @ (1312 × 768), o=8 column duplicates o=0.
//
// R14: producer/consumer WAVE SPECIALIZATION at unchanged per-CU traffic.
// Survivor model after R3-R13: per-chunk cost = serial sum of phases
// (MFMA + TA/L1-fill + commit-VALU) because lockstep waves all run every
// phase. Split: 4 producer waves (gather/interp/ds_write, no MFMA/acc) +
// 12 consumer waves (loadB/ds_read/MFMA/epilogue, no gathers), 1024 thr,
// launch_bounds(1024,4). Consumer tile 64x64 (acc[4][4]=64 regs, single
// bf[4] set -> ~105 regs; producer ~90). B bytes, gather count, bary all
// identical to R7/R8. A/B vs R13 isolates the role split.

typedef __attribute__((ext_vector_type(8))) short short8;
typedef __attribute__((ext_vector_type(4))) float floatx4;
typedef __attribute__((ext_vector_type(2))) float fx2;

#define KPTS 100000
#define OUT_STRIDE 864        // floats per k-row (9*96)
#define BM 64
#define THREADS 1024
#define BP_SHORTS 1007616     // 41*48*64*8

// Workgroup barrier without vmcnt drain (R7/R8 form).
#define BARRIER() do {                              \
    __builtin_amdgcn_sched_barrier(0);              \
    asm volatile("s_waitcnt lgkmcnt(0)");           \
    __builtin_amdgcn_s_barrier();                   \
  } while (0)

__device__ __forceinline__ short f2bf(float x) {
  union { float f; uint32_t u; } c; c.f = x;
  uint32_t u = c.u;
  u += 0x7FFFu + ((u >> 16) & 1u);   // round-to-nearest-even
  return (short)(u >> 16);
}
__device__ __forceinline__ float bf2f(short s) {
  union { uint32_t u; float f; } c;
  c.u = ((uint32_t)(uint16_t)s) << 16;
  return c.f;
}

// ---------------- prep: ms -> bf16 table --------------------------------
__global__ void prep_ms(const float* __restrict__ ms, short* __restrict__ msb) {
  const int i = (blockIdx.x * 256 + threadIdx.x) * 8;
  if (i < KPTS * 32) {
    floatx4 a = *(const floatx4*)(ms + i);
    floatx4 b = *(const floatx4*)(ms + i + 4);
    short8 s;
#pragma unroll
    for (int j = 0; j < 4; ++j) { s[j] = f2bf(a[j]); s[4 + j] = f2bf(b[j]); }
    *reinterpret_cast<short8*>(msb + i) = s;
  }
}

// ---------------- prep: pack B in MFMA fragment layout --------------------
// Bp[ch][ntile][lane][j] = B[c = ch*32 + (lane>>4)*8 + j][n = ntile*16 + (lane&15)]
__global__ void prep_B(const float* __restrict__ kern,
                       const float* __restrict__ tw,
                       const float* __restrict__ sw,
                       short* __restrict__ Bp) {
  const int ntile = blockIdx.x;   // 0..47
  const int ch    = blockIdx.y;   // 0..40
  const int lane  = threadIdx.x;  // 0..63
  const int n = ntile * 16 + (lane & 15);
  const int o = n / 96;
  const int t = n - o * 96;
  const int fb = (lane >> 4) * 8;

  short8 v;
  if (ch < 40) {
    float kcol[40];
#pragma unroll
    for (int ra = 0; ra < 40; ++ra) kcol[ra] = kern[ra * 40 + ch];
#pragma unroll
    for (int j = 0; j < 8; ++j) {
      const int f = fb + j;
      float acc = 0.f;
      for (int r = 0; r < 5; ++r) {
#pragma unroll
        for (int a = 0; a < 8; ++a) {
          acc += kcol[r * 8 + a] * tw[((t * 5 + r) * 8 + ((a + o) & 7)) * 32 + f];
        }
      }
      v[j] = f2bf(acc);
    }
  } else {
#pragma unroll
    for (int j = 0; j < 8; ++j) v[j] = f2bf(sw[t * 32 + fb + j]);
  }
  *reinterpret_cast<short8*>(Bp + ((size_t)(ch * 48 + ntile) * 64 + lane) * 8) = v;
}

// ---------------- main fused GEMM (4 producer + 12 consumer waves) --------
__global__ __launch_bounds__(THREADS, 4) void conv_main(
    const short* __restrict__ msb,
    const float* __restrict__ bary,
    const float* __restrict__ bias,
    const short* __restrict__ Bp,
    float* __restrict__ out) {
  __shared__ short Atile[2][BM][40];   // 32 used cols + 8 pad shorts

  const int kbase = blockIdx.x * BM;
  const int tid = threadIdx.x;
  const int lane = tid & 63;
  const int l15 = lane & 15;
  const int kh = lane >> 4;            // 0..3

  // roles: waves 0-3 = producers (A-build), waves 4-15 = consumers (GEMM)
  const bool builder = tid < 256;
  const bool consumer = tid >= 256;
  const int wng = (tid >> 6) - 4;      // consumer col group 0..11 (cols wng*64)

  // producer A-build: 4 threads per row, 8 bf16 f-columns each (R8-verbatim)
  const int arow = tid >> 2;           // 0..63 for builders
  const int af0 = (tid & 3) * 8;       // 0,8,16,24
  const int krow = kbase + (arow & 63);
  const bool rowok = builder && (krow < KPTS);
  const float* __restrict__ brow = bary + (size_t)(rowok ? krow : 0) * 240;
  const short* __restrict__ mrowb = msb + (size_t)(rowok ? krow : 0) * 32 + af0;

  // bary register sets (chunk parity): loaded 1 iter before use
  fx2 bE0, bE1, bE2, bO0, bO1, bO2;
  // gather register sets (chunk parity): issued 1 full window before commit
  short8 eG0, eG1, eG2, oG0, oG1, oG2;
  float eW0, eW1, eW2, oW0, oW1, oW2;

  auto ldbary = [&](int c, fx2& p0, fx2& p1, fx2& p2) {
    if (rowok) {
      const fx2* bp = (const fx2*)(brow + c * 6);
      p0 = __builtin_nontemporal_load(bp);
      p1 = __builtin_nontemporal_load(bp + 1);
      p2 = __builtin_nontemporal_load(bp + 2);
    } else {
      p0 = (fx2)0.f; p1 = (fx2)0.f; p2 = (fx2)0.f;
    }
  };
  auto issueG = [&](int c, const fx2& p0, const fx2& p1, const fx2& p2,
                    short8& A, short8& B, short8& C,
                    float& W0, float& W1, float& W2) {
    if (c == 40) {   // center chunk: pass-through
      A = *(const short8*)(mrowb);
      B = A; C = A;
      W0 = rowok ? 1.f : 0.f; W1 = 0.f; W2 = 0.f;
    } else {
      A = *(const short8*)(msb + ((size_t)(int)p0.x) * 32 + af0);
      B = *(const short8*)(msb + ((size_t)(int)p1.x) * 32 + af0);
      C = *(const short8*)(msb + ((size_t)(int)p2.x) * 32 + af0);
      W0 = p0.y; W1 = p1.y; W2 = p2.y;
    }
  };
  auto commitG = [&](const short8& A, const short8& B, const short8& C,
                     float W0, float W1, float W2, int buf) {
    short8 s;
#pragma unroll
    for (int j = 0; j < 8; ++j)
      s[j] = f2bf(W0 * bf2f(A[j]) + W1 * bf2f(B[j]) + W2 * bf2f(C[j]));
    *reinterpret_cast<short8*>(&Atile[buf][arow][af0]) = s;
  };

  // consumer state: single B-fragment set, loaded at window top (L2-hit
  // latency covered by the 2 other consumer waves on the SIMD)
  short8 bf[4];
  auto loadB = [&](int c) {
    const short* bp = Bp + ((size_t)(c * 48 + wng * 4) * 64 + lane) * 8;
#pragma unroll
    for (int j = 0; j < 4; ++j)
      bf[j] = *reinterpret_cast<const short8*>(bp + (size_t)j * 512);
  };

  floatx4 acc[4][4];
#pragma unroll
  for (int mi = 0; mi < 4; ++mi)
#pragma unroll
    for (int nj = 0; nj < 4; ++nj) acc[mi][nj] = (floatx4)0.f;

  // ---- prologue (producers build chunk 0; one exposed stall, once) ----
  if (builder) {
    fx2 t0, t1, t2;
    ldbary(0, t0, t1, t2);
    issueG(0, t0, t1, t2, eG0, eG1, eG2, eW0, eW1, eW2);
    ldbary(1, t0, t1, t2);
    issueG(1, t0, t1, t2, oG0, oG1, oG2, oW0, oW1, oW2);
    ldbary(2, bE0, bE1, bE2);                  // for issue(2) at window 0
    commitG(eG0, eG1, eG2, eW0, eW1, eW2, 0);  // chunk 0 -> Atile[0]
  }
  BARRIER();

  // window ch: producers issue gathers(ch+2) + refill bary(ch+3), commit
  // chunk ch+1 -> Atile[(ch&1)^1]. consumers loadB(ch) + ds_read af +
  // 16 MFMA on Atile[ch&1]. One barrier per window; global loads stay
  // in flight across it (counted vmcnt at use).
#define ITER(ch, UB0, UB1, UB2, FB0, FB1, FB2,                                  \
             FG0, FG1, FG2, FW0, FW1, FW2,                                      \
             CG0, CG1, CG2, CW0, CW1, CW2, CUR)                                 \
  {                                                                             \
    if (builder) {                                                              \
      if ((ch) + 2 <= 40)                                                       \
        issueG((ch) + 2, UB0, UB1, UB2, FG0, FG1, FG2, FW0, FW1, FW2);          \
      if ((ch) + 3 <= 39) ldbary((ch) + 3, FB0, FB1, FB2);                      \
    }                                                                           \
    if (consumer) {                                                             \
      loadB(ch);                                                                \
      short8 af[4];                                                             \
      _Pragma("unroll")                                                         \
      for (int mi = 0; mi < 4; ++mi)                                            \
        af[mi] = *reinterpret_cast<const short8*>(&Atile[CUR][mi * 16 + l15][kh * 8]); \
      _Pragma("unroll")                                                         \
      for (int nj = 0; nj < 4; ++nj)                                            \
        _Pragma("unroll")                                                       \
        for (int mi = 0; mi < 4; ++mi)                                          \
          acc[mi][nj] = __builtin_amdgcn_mfma_f32_16x16x32_bf16(af[mi], bf[nj], \
                                                                acc[mi][nj], 0, 0, 0); \
    }                                                                           \
    if (builder && (ch) + 1 <= 40)                                              \
      commitG(CG0, CG1, CG2, CW0, CW1, CW2, (CUR) ^ 1);                         \
    BARRIER();                                                                  \
  }

  for (int ch = 0; ch < 40; ch += 2) {
    // even window: fill E gathers (ch+2), commit O gathers (ch+1); Atile[0]
    ITER(ch,     bE0, bE1, bE2, bO0, bO1, bO2,
         eG0, eG1, eG2, eW0, eW1, eW2,
         oG0, oG1, oG2, oW0, oW1, oW2, 0)
    // odd window: fill O gathers (ch+3), commit E gathers (ch+2); Atile[1]
    ITER(ch + 1, bO0, bO1, bO2, bE0, bE1, bE2,
         oG0, oG1, oG2, oW0, oW1, oW2,
         eG0, eG1, eG2, eW0, eW1, eW2, 1)
  }
  ITER(40, bE0, bE1, bE2, bO0, bO1, bO2,
       eG0, eG1, eG2, eW0, eW1, eW2,
       oG0, oG1, oG2, oW0, oW1, oW2, 0)
#undef ITER

  // epilogue (consumers only): bias + relu; out[k*864 + n]; o=8 dup of o=0
  if (consumer) {
#pragma unroll
    for (int mi = 0; mi < 4; ++mi) {
      const int rb = kbase + mi * 16 + kh * 4;
#pragma unroll
      for (int nj = 0; nj < 4; ++nj) {
        const int n = wng * 64 + nj * 16 + l15;
        const float bsv = bias[(wng * 64 + nj * 16) % 96 + l15];
        const bool dup = (n < 96);
#pragma unroll
        for (int i = 0; i < 4; ++i) {
          const int r = rb + i;
          if (r < KPTS) {
            float vv = fmaxf(acc[mi][nj][i] + bsv, 0.f);
            out[(size_t)r * OUT_STRIDE + n] = vv;
            if (dup) out[(size_t)r * OUT_STRIDE + 768 + n] = vv;
          }
        }
      }
    }
  }
}

extern "C" void kernel_launch(void* const* d_in, const int* in_sizes, int n_in,
                              void* d_out, int out_size, void* d_ws, size_t ws_size,
                              hipStream_t stream) {
  const float* ms   = (const float*)d_in[0];  // (K,32)
  const float* bary = (const float*)d_in[1];  // (K,5,8,3,2)
  const float* kern = (const float*)d_in[2];  // (5,8,5,8)
  const float* tw   = (const float*)d_in[3];  // (96,5,8,32)
  const float* sw   = (const float*)d_in[4];  // (96,1,32)
  const float* bias = (const float*)d_in[5];  // (96,)
  float* out = (float*)d_out;
  short* Bp  = (short*)d_ws;                  // 2.02 MB
  short* msb = (short*)d_ws + BP_SHORTS;      // bf16 ms table, 6.4 MB

  hipLaunchKernelGGL(prep_B, dim3(48, 41), dim3(64), 0, stream, kern, tw, sw, Bp);
  hipLaunchKernelGGL(prep_ms, dim3((KPTS * 32 / 8 + 255) / 256), dim3(256), 0, stream,
                     ms, msb);
  hipLaunchKernelGGL(conv_main, dim3(1563), dim3(THREADS), 0, stream,
                     msb, bary, bias, Bp, out);
}

// Round 16
// 452.955 us; speedup vs baseline: 2.6019x; 2.6019x over previous
//
#include <hip/hip_runtime.h>
#include <hip/hip_bf16.h>
#include <stdint.h>

// ConvIntrinsic: fused  out[k,o,t] = relu( Σ_f sw[t,f]·ms[k,f]
//                + Σ_{x,y,f} W3[o,t,x,y,f]·interp0[k,x,y,f] + bias[t] )
// => GEMM (K=100000 × 1312) @ (1312 × 768), o=8 column duplicates o=0.
//
// R15: CHAMPION RESTORE (R7 verbatim, 455 µs measured). 15-round summary:
//  - structure: BM=64, 8 waves 64x96, A built in LDS from 2-ahead-pipelined
//    random ms gathers, B pre-packed in MFMA fragment layout (L2-resident),
//    one barrier per K-chunk (R7 non-draining form).
//  - falsified levers: barrier flavor (R3/R4/R7 null), window batching
//    (R9 -12%), occupancy+traffic (R6/R12 -2x), occupancy traffic-neutral
//    (R13 -30%), kernel split (R10/R11 -70%), EA-byte cut (R8 -6%),
//    wave specialization (R14: register spill, -160%).
//  - surviving model: ~4370 cy/window fixed serialization of the fused
//    gather->commit->MFMA phase chain at 2 waves/SIMD; not addressable at
//    HIP source level in this design space.

typedef __attribute__((ext_vector_type(8))) short short8;
typedef __attribute__((ext_vector_type(4))) short short4v;
typedef __attribute__((ext_vector_type(4))) float floatx4;
typedef __attribute__((ext_vector_type(2))) float fx2;

#define KPTS 100000
#define OUT_STRIDE 864   // 9*96
#define BM 64
#define THREADS 512

// Workgroup barrier that does NOT drain vmcnt:
//  - sched_barrier(0): nothing from above (esp. the commit ds_write) sinks below
//  - bare lgkmcnt(0): waits the ds_write; no "memory" clobber -> no vmcnt drain
//  - s_barrier intrinsic: memory ops can't be scheduled across it (side effects)
#define BARRIER() do {                              \
    __builtin_amdgcn_sched_barrier(0);              \
    asm volatile("s_waitcnt lgkmcnt(0)");           \
    __builtin_amdgcn_s_barrier();                   \
  } while (0)

__device__ __forceinline__ short f2bf(float x) {
  union { float f; uint32_t u; } c; c.f = x;
  uint32_t u = c.u;
  u += 0x7FFFu + ((u >> 16) & 1u);   // round-to-nearest-even
  return (short)(u >> 16);
}

// ---------------- prep: pack B in MFMA fragment layout --------------------
// Bp[ch][ntile][lane][j] = B[c = ch*32 + (lane>>4)*8 + j][n = ntile*16 + (lane&15)]
__global__ void prep_B(const float* __restrict__ kern,
                       const float* __restrict__ tw,
                       const float* __restrict__ sw,
                       short* __restrict__ Bp) {
  const int ntile = blockIdx.x;   // 0..47
  const int ch    = blockIdx.y;   // 0..40
  const int lane  = threadIdx.x;  // 0..63
  const int n = ntile * 16 + (lane & 15);
  const int o = n / 96;
  const int t = n - o * 96;
  const int fb = (lane >> 4) * 8;

  short8 v;
  if (ch < 40) {
    float kcol[40];
#pragma unroll
    for (int ra = 0; ra < 40; ++ra) kcol[ra] = kern[ra * 40 + ch];
#pragma unroll
    for (int j = 0; j < 8; ++j) {
      const int f = fb + j;
      float acc = 0.f;
      for (int r = 0; r < 5; ++r) {
#pragma unroll
        for (int a = 0; a < 8; ++a) {
          acc += kcol[r * 8 + a] * tw[((t * 5 + r) * 8 + ((a + o) & 7)) * 32 + f];
        }
      }
      v[j] = f2bf(acc);
    }
  } else {
#pragma unroll
    for (int j = 0; j < 8; ++j) v[j] = f2bf(sw[t * 32 + fb + j]);
  }
  *reinterpret_cast<short8*>(Bp + ((size_t)(ch * 48 + ntile) * 64 + lane) * 8) = v;
}

// ---------------- main fused GEMM ----------------------------------------
__global__ __launch_bounds__(THREADS, 1) void conv_main(
    const float* __restrict__ ms,
    const float* __restrict__ bary,
    const float* __restrict__ bias,
    const short* __restrict__ Bp,
    float* __restrict__ out) {
  __shared__ short Atile[2][BM][40];   // stride 40 shorts: conflict-free

  const int kbase = blockIdx.x * BM;
  const int tid = threadIdx.x;
  const int lane = tid & 63;
  const int wn = tid >> 6;             // 0..7  (wave n-group: cols wn*96)
  const int l15 = lane & 15;
  const int kh = lane >> 4;            // 0..3

  // A-build role: 8 threads per row, 4 f-columns each
  const int arow = tid >> 3;           // 0..63
  const int af0 = (tid & 7) * 4;       // 0,4,...,28
  const int krow = kbase + arow;
  const bool rowok = krow < KPTS;
  const float* __restrict__ brow = bary + (size_t)(rowok ? krow : 0) * 240;

  // bary register sets (chunk parity): loaded 1 iter before use
  fx2 bE0, bE1, bE2, bO0, bO1, bO2;
  // gather register sets (chunk parity): issued 1 full iter before commit
  floatx4 eG0, eG1, eG2, oG0, oG1, oG2;
  float eW0, eW1, eW2, oW0, oW1, oW2;

  auto ldbary = [&](int c, fx2& p0, fx2& p1, fx2& p2) {
    if (rowok) {
      const fx2* bp = (const fx2*)(brow + c * 6);
      p0 = __builtin_nontemporal_load(bp);
      p1 = __builtin_nontemporal_load(bp + 1);
      p2 = __builtin_nontemporal_load(bp + 2);
    } else {
      p0 = (fx2)0.f; p1 = (fx2)0.f; p2 = (fx2)0.f;
    }
  };
  auto issueG = [&](int c, const fx2& p0, const fx2& p1, const fx2& p2,
                    floatx4& A, floatx4& B, floatx4& C,
                    float& W0, float& W1, float& W2) {
    if (c == 40) {   // center chunk: A[k][1280+f] = ms[k][f]
      A = *(const floatx4*)(ms + (size_t)(rowok ? krow : 0) * 32 + af0);
      B = (floatx4)0.f; C = (floatx4)0.f;
      W0 = rowok ? 1.f : 0.f; W1 = 0.f; W2 = 0.f;
    } else {
      A = *(const floatx4*)(ms + ((size_t)(int)p0.x) * 32 + af0);
      B = *(const floatx4*)(ms + ((size_t)(int)p1.x) * 32 + af0);
      C = *(const floatx4*)(ms + ((size_t)(int)p2.x) * 32 + af0);
      W0 = p0.y; W1 = p1.y; W2 = p2.y;
    }
  };
  auto commitG = [&](const floatx4& A, const floatx4& B, const floatx4& C,
                     float W0, float W1, float W2, int buf) {
    short4v s;
    s[0] = f2bf(W0 * A[0] + W1 * B[0] + W2 * C[0]);
    s[1] = f2bf(W0 * A[1] + W1 * B[1] + W2 * C[1]);
    s[2] = f2bf(W0 * A[2] + W1 * B[2] + W2 * C[2]);
    s[3] = f2bf(W0 * A[3] + W1 * B[3] + W2 * C[3]);
    *reinterpret_cast<short4v*>(&Atile[buf][arow][af0]) = s;
  };

  short8 bfA[6], bfB[6];
  auto loadB = [&](int c, short8* dst) {
    const short* bp = Bp + ((size_t)(c * 48 + wn * 6) * 64 + lane) * 8;
#pragma unroll
    for (int j = 0; j < 6; ++j)
      dst[j] = *reinterpret_cast<const short8*>(bp + (size_t)j * 512);
  };

  floatx4 acc[4][6];
#pragma unroll
  for (int mi = 0; mi < 4; ++mi)
#pragma unroll
    for (int nj = 0; nj < 6; ++nj) acc[mi][nj] = (floatx4)0.f;

  // ---- prologue ----
  {
    fx2 t0, t1, t2;
    ldbary(0, t0, t1, t2);
    issueG(0, t0, t1, t2, eG0, eG1, eG2, eW0, eW1, eW2);
    ldbary(1, t0, t1, t2);
    issueG(1, t0, t1, t2, oG0, oG1, oG2, oW0, oW1, oW2);
  }
  ldbary(2, bE0, bE1, bE2);           // for issue(2) at iter 0
  commitG(eG0, eG1, eG2, eW0, eW1, eW2, 0);   // chunk 0 -> Atile[0]
  loadB(0, bfA);
  BARRIER();

  // iter ch: issue(ch+2) with bary set (ch&1); ldbary(ch+3) -> other set;
  // MFMA chunk ch from Atile[ch&1] with B-set BF; loadB(ch+1) -> NBF;
  // commit(ch+1) -> Atile[(ch&1)^1]; barrier (global loads stay in flight).
#define ITER(ch, UB0, UB1, UB2, FB0, FB1, FB2,                                  \
             FG0, FG1, FG2, FW0, FW1, FW2,                                      \
             CG0, CG1, CG2, CW0, CW1, CW2, CUR, BF, NBF)                        \
  {                                                                             \
    if ((ch) + 2 <= 40)                                                         \
      issueG((ch) + 2, UB0, UB1, UB2, FG0, FG1, FG2, FW0, FW1, FW2);            \
    if ((ch) + 3 <= 39) ldbary((ch) + 3, FB0, FB1, FB2);                        \
    short8 af[4];                                                               \
    _Pragma("unroll")                                                           \
    for (int mi = 0; mi < 4; ++mi)                                              \
      af[mi] = *reinterpret_cast<const short8*>(&Atile[CUR][mi * 16 + l15][kh * 8]); \
    if ((ch) + 1 <= 40) loadB((ch) + 1, NBF);                                   \
    _Pragma("unroll")                                                           \
    for (int nj = 0; nj < 6; ++nj)                                              \
      _Pragma("unroll")                                                         \
      for (int mi = 0; mi < 4; ++mi)                                            \
        acc[mi][nj] = __builtin_amdgcn_mfma_f32_16x16x32_bf16(af[mi], BF[nj],   \
                                                              acc[mi][nj], 0, 0, 0); \
    if ((ch) + 1 <= 40)                                                         \
      commitG(CG0, CG1, CG2, CW0, CW1, CW2, (CUR) ^ 1);                         \
    BARRIER();                                                                  \
  }

  for (int ch = 0; ch < 40; ch += 2) {
    // even iter: use bE, fill bO; fill E gathers, commit O gathers; Atile[0]; B=bfA
    ITER(ch,     bE0, bE1, bE2, bO0, bO1, bO2,
         eG0, eG1, eG2, eW0, eW1, eW2,
         oG0, oG1, oG2, oW0, oW1, oW2, 0, bfA, bfB)
    // odd iter: use bO, fill bE; fill O gathers, commit E gathers; Atile[1]; B=bfB
    ITER(ch + 1, bO0, bO1, bO2, bE0, bE1, bE2,
         oG0, oG1, oG2, oW0, oW1, oW2,
         eG0, eG1, eG2, eW0, eW1, eW2, 1, bfB, bfA)
  }
  ITER(40, bE0, bE1, bE2, bO0, bO1, bO2,
       eG0, eG1, eG2, eW0, eW1, eW2,
       oG0, oG1, oG2, oW0, oW1, oW2, 0, bfA, bfB)
#undef ITER

  // epilogue: bias + relu; out[k,o,t] = out[k*864 + n]; o=8 duplicates o=0
#pragma unroll
  for (int mi = 0; mi < 4; ++mi) {
    const int rb = kbase + mi * 16 + kh * 4;
#pragma unroll
    for (int nj = 0; nj < 6; ++nj) {
      const int n = wn * 96 + nj * 16 + l15;
      const float bsv = bias[nj * 16 + l15];
      const bool dup = (wn == 0);
#pragma unroll
      for (int i = 0; i < 4; ++i) {
        const int r = rb + i;
        if (r < KPTS) {
          float vv = fmaxf(acc[mi][nj][i] + bsv, 0.f);
          out[(size_t)r * OUT_STRIDE + n] = vv;
          if (dup) out[(size_t)r * OUT_STRIDE + 768 + n] = vv;
        }
      }
    }
  }
}

extern "C" void kernel_launch(void* const* d_in, const int* in_sizes, int n_in,
                              void* d_out, int out_size, void* d_ws, size_t ws_size,
                              hipStream_t stream) {
  const float* ms   = (const float*)d_in[0];  // (K,32)
  const float* bary = (const float*)d_in[1];  // (K,5,8,3,2)
  const float* kern = (const float*)d_in[2];  // (5,8,5,8)
  const float* tw   = (const float*)d_in[3];  // (96,5,8,32)
  const float* sw   = (const float*)d_in[4];  // (96,1,32)
  const float* bias = (const float*)d_in[5];  // (96,)
  float* out = (float*)d_out;
  short* Bp = (short*)d_ws;                   // 41*48*64*8 bf16 ≈ 2.02 MB

  hipLaunchKernelGGL(prep_B, dim3(48, 41), dim3(64), 0, stream, kern, tw, sw, Bp);
  hipLaunchKernelGGL(conv_main, dim3(1563), dim3(THREADS), 0, stream,
                     ms, bary, bias, Bp, out);
}

// Round 17
// 447.218 us; speedup vs baseline: 2.6353x; 1.0128x over previous
//
#include <hip/hip_runtime.h>
#include <hip/hip_bf16.h>
#include <stdint.h>

// ConvIntrinsic: fused  out[k,o,t] = relu( Σ_f sw[t,f]·ms[k,f]
//                + Σ_{x,y,f} W3[o,t,x,y,f]·interp0[k,x,y,f] + bias[t] )
// => GEMM (K=100000 × 1312) @ (1312 × 768), o=8 column duplicates o=0.
//
// R16: champion (R7/R15) with FP16 datapath. Mechanism: per-window cost is
// work-proportional (R9); L1/TCP line delivery (~1250 cy/chunk: B 768 +
// fp32-gather 384 + bary) is the largest throughput component after MFMA.
// fp16 ms-table makes a vertex row 64 B = ONE line (gather lines halve, the
// R8 win) while packed v_pk_fma_f16 keeps commit VALU BELOW the fp32
// champion (the R8 loss), and mfma_f32_16x16x32_f16 runs at the bf16 rate
// with fp32 accumulate. Precision improves (fp16: 10 mantissa bits vs
// bf16's 7). Pipeline/barrier/epilogue champion-verbatim.

typedef __attribute__((ext_vector_type(8))) short short8;
typedef __attribute__((ext_vector_type(8))) _Float16 half8;
typedef __attribute__((ext_vector_type(4))) _Float16 half4;
typedef __attribute__((ext_vector_type(4))) float floatx4;
typedef __attribute__((ext_vector_type(2))) float fx2;

#define KPTS 100000
#define OUT_STRIDE 864   // 9*96
#define BM 64
#define THREADS 512
#define BP_HALVES 1007616   // 41*48*64*8 (fp16 Bp element count)

// Workgroup barrier that does NOT drain vmcnt (champion form).
#define BARRIER() do {                              \
    __builtin_amdgcn_sched_barrier(0);              \
    asm volatile("s_waitcnt lgkmcnt(0)");           \
    __builtin_amdgcn_s_barrier();                   \
  } while (0)

// ---------------- prep: ms -> fp16 table --------------------------------
__global__ void prep_msh(const float* __restrict__ ms, _Float16* __restrict__ msh) {
  const int i = (blockIdx.x * 256 + threadIdx.x) * 8;
  if (i < KPTS * 32) {
    floatx4 a = *(const floatx4*)(ms + i);
    floatx4 b = *(const floatx4*)(ms + i + 4);
    half8 h;
#pragma unroll
    for (int j = 0; j < 4; ++j) {
      h[j] = (_Float16)a[j];
      h[4 + j] = (_Float16)b[j];
    }
    *reinterpret_cast<half8*>(msh + i) = h;
  }
}

// ---------------- prep: pack B (fp16) in MFMA fragment layout -------------
// Bp[ch][ntile][lane][j] = B[c = ch*32 + (lane>>4)*8 + j][n = ntile*16 + (lane&15)]
__global__ void prep_B(const float* __restrict__ kern,
                       const float* __restrict__ tw,
                       const float* __restrict__ sw,
                       _Float16* __restrict__ Bp) {
  const int ntile = blockIdx.x;   // 0..47
  const int ch    = blockIdx.y;   // 0..40
  const int lane  = threadIdx.x;  // 0..63
  const int n = ntile * 16 + (lane & 15);
  const int o = n / 96;
  const int t = n - o * 96;
  const int fb = (lane >> 4) * 8;

  half8 v;
  if (ch < 40) {
    float kcol[40];
#pragma unroll
    for (int ra = 0; ra < 40; ++ra) kcol[ra] = kern[ra * 40 + ch];
#pragma unroll
    for (int j = 0; j < 8; ++j) {
      const int f = fb + j;
      float acc = 0.f;
      for (int r = 0; r < 5; ++r) {
#pragma unroll
        for (int a = 0; a < 8; ++a) {
          acc += kcol[r * 8 + a] * tw[((t * 5 + r) * 8 + ((a + o) & 7)) * 32 + f];
        }
      }
      v[j] = (_Float16)acc;
    }
  } else {
#pragma unroll
    for (int j = 0; j < 8; ++j) v[j] = (_Float16)sw[t * 32 + fb + j];
  }
  *reinterpret_cast<half8*>(Bp + ((size_t)(ch * 48 + ntile) * 64 + lane) * 8) = v;
}

// ---------------- main fused GEMM ----------------------------------------
__global__ __launch_bounds__(THREADS, 1) void conv_main(
    const _Float16* __restrict__ msh,
    const float* __restrict__ bary,
    const float* __restrict__ bias,
    const _Float16* __restrict__ Bp,
    float* __restrict__ out) {
  __shared__ _Float16 Atile[2][BM][40];   // 32 used halves + 8 pad (80 B stride)

  const int kbase = blockIdx.x * BM;
  const int tid = threadIdx.x;
  const int lane = tid & 63;
  const int wn = tid >> 6;             // 0..7  (wave n-group: cols wn*96)
  const int l15 = lane & 15;
  const int kh = lane >> 4;            // 0..3

  // A-build role: 8 threads per row, 4 fp16 f-columns each (8 B loads)
  const int arow = tid >> 3;           // 0..63
  const int af0 = (tid & 7) * 4;       // 0,4,...,28 (half index)
  const int krow = kbase + arow;
  const bool rowok = krow < KPTS;
  const float* __restrict__ brow = bary + (size_t)(rowok ? krow : 0) * 240;
  const _Float16* __restrict__ mrowh = msh + (size_t)(rowok ? krow : 0) * 32 + af0;

  // bary register sets (chunk parity): loaded 1 iter before use
  fx2 bE0, bE1, bE2, bO0, bO1, bO2;
  // gather register sets (chunk parity): issued 1 full iter before commit
  half4 eG0, eG1, eG2, oG0, oG1, oG2;
  float eW0, eW1, eW2, oW0, oW1, oW2;

  auto ldbary = [&](int c, fx2& p0, fx2& p1, fx2& p2) {
    if (rowok) {
      const fx2* bp = (const fx2*)(brow + c * 6);
      p0 = __builtin_nontemporal_load(bp);
      p1 = __builtin_nontemporal_load(bp + 1);
      p2 = __builtin_nontemporal_load(bp + 2);
    } else {
      p0 = (fx2)0.f; p1 = (fx2)0.f; p2 = (fx2)0.f;
    }
  };
  auto issueG = [&](int c, const fx2& p0, const fx2& p1, const fx2& p2,
                    half4& A, half4& B, half4& C,
                    float& W0, float& W1, float& W2) {
    if (c == 40) {   // center chunk: A[k][1280+f] = ms[k][f] (pass-through)
      A = *(const half4*)(mrowh);
      B = (half4)(_Float16)0.f; C = B;
      W0 = rowok ? 1.f : 0.f; W1 = 0.f; W2 = 0.f;
    } else {
      A = *(const half4*)(msh + ((size_t)(int)p0.x) * 32 + af0);
      B = *(const half4*)(msh + ((size_t)(int)p1.x) * 32 + af0);
      C = *(const half4*)(msh + ((size_t)(int)p2.x) * 32 + af0);
      W0 = p0.y; W1 = p1.y; W2 = p2.y;
    }
  };
  auto commitG = [&](const half4& A, const half4& B, const half4& C,
                     float W0, float W1, float W2, int buf) {
    const _Float16 w0 = (_Float16)W0, w1 = (_Float16)W1, w2 = (_Float16)W2;
    half4 s = A * w0;                  // v_pk_fma_f16 pairs
    s += B * w1;
    s += C * w2;
    *reinterpret_cast<half4*>(&Atile[buf][arow][af0]) = s;
  };

  half8 bfA[6], bfB[6];
  auto loadB = [&](int c, half8* dst) {
    const _Float16* bp = Bp + ((size_t)(c * 48 + wn * 6) * 64 + lane) * 8;
#pragma unroll
    for (int j = 0; j < 6; ++j)
      dst[j] = *reinterpret_cast<const half8*>(bp + (size_t)j * 512);
  };

  floatx4 acc[4][6];
#pragma unroll
  for (int mi = 0; mi < 4; ++mi)
#pragma unroll
    for (int nj = 0; nj < 6; ++nj) acc[mi][nj] = (floatx4)0.f;

  // ---- prologue ----
  {
    fx2 t0, t1, t2;
    ldbary(0, t0, t1, t2);
    issueG(0, t0, t1, t2, eG0, eG1, eG2, eW0, eW1, eW2);
    ldbary(1, t0, t1, t2);
    issueG(1, t0, t1, t2, oG0, oG1, oG2, oW0, oW1, oW2);
  }
  ldbary(2, bE0, bE1, bE2);           // for issue(2) at iter 0
  commitG(eG0, eG1, eG2, eW0, eW1, eW2, 0);   // chunk 0 -> Atile[0]
  loadB(0, bfA);
  BARRIER();

  // iter ch: issue(ch+2) with bary set (ch&1); ldbary(ch+3) -> other set;
  // MFMA chunk ch from Atile[ch&1] with B-set BF; loadB(ch+1) -> NBF;
  // commit(ch+1) -> Atile[(ch&1)^1]; barrier (global loads stay in flight).
#define ITER(ch, UB0, UB1, UB2, FB0, FB1, FB2,                                  \
             FG0, FG1, FG2, FW0, FW1, FW2,                                      \
             CG0, CG1, CG2, CW0, CW1, CW2, CUR, BF, NBF)                        \
  {                                                                             \
    if ((ch) + 2 <= 40)                                                         \
      issueG((ch) + 2, UB0, UB1, UB2, FG0, FG1, FG2, FW0, FW1, FW2);            \
    if ((ch) + 3 <= 39) ldbary((ch) + 3, FB0, FB1, FB2);                        \
    half8 af[4];                                                                \
    _Pragma("unroll")                                                           \
    for (int mi = 0; mi < 4; ++mi)                                              \
      af[mi] = *reinterpret_cast<const half8*>(&Atile[CUR][mi * 16 + l15][kh * 8]); \
    if ((ch) + 1 <= 40) loadB((ch) + 1, NBF);                                   \
    _Pragma("unroll")                                                           \
    for (int nj = 0; nj < 6; ++nj)                                              \
      _Pragma("unroll")                                                         \
      for (int mi = 0; mi < 4; ++mi)                                            \
        acc[mi][nj] = __builtin_amdgcn_mfma_f32_16x16x32_f16(af[mi], BF[nj],    \
                                                             acc[mi][nj], 0, 0, 0); \
    if ((ch) + 1 <= 40)                                                         \
      commitG(CG0, CG1, CG2, CW0, CW1, CW2, (CUR) ^ 1);                         \
    BARRIER();                                                                  \
  }

  for (int ch = 0; ch < 40; ch += 2) {
    // even iter: use bE, fill bO; fill E gathers, commit O gathers; Atile[0]; B=bfA
    ITER(ch,     bE0, bE1, bE2, bO0, bO1, bO2,
         eG0, eG1, eG2, eW0, eW1, eW2,
         oG0, oG1, oG2, oW0, oW1, oW2, 0, bfA, bfB)
    // odd iter: use bO, fill bE; fill O gathers, commit E gathers; Atile[1]; B=bfB
    ITER(ch + 1, bO0, bO1, bO2, bE0, bE1, bE2,
         oG0, oG1, oG2, oW0, oW1, oW2,
         eG0, eG1, eG2, eW0, eW1, eW2, 1, bfB, bfA)
  }
  ITER(40, bE0, bE1, bE2, bO0, bO1, bO2,
       eG0, eG1, eG2, eW0, eW1, eW2,
       oG0, oG1, oG2, oW0, oW1, oW2, 0, bfA, bfB)
#undef ITER

  // epilogue: bias + relu; out[k,o,t] = out[k*864 + n]; o=8 duplicates o=0
#pragma unroll
  for (int mi = 0; mi < 4; ++mi) {
    const int rb = kbase + mi * 16 + kh * 4;
#pragma unroll
    for (int nj = 0; nj < 6; ++nj) {
      const int n = wn * 96 + nj * 16 + l15;
      const float bsv = bias[nj * 16 + l15];
      const bool dup = (wn == 0);
#pragma unroll
      for (int i = 0; i < 4; ++i) {
        const int r = rb + i;
        if (r < KPTS) {
          float vv = fmaxf(acc[mi][nj][i] + bsv, 0.f);
          out[(size_t)r * OUT_STRIDE + n] = vv;
          if (dup) out[(size_t)r * OUT_STRIDE + 768 + n] = vv;
        }
      }
    }
  }
}

extern "C" void kernel_launch(void* const* d_in, const int* in_sizes, int n_in,
                              void* d_out, int out_size, void* d_ws, size_t ws_size,
                              hipStream_t stream) {
  const float* ms   = (const float*)d_in[0];  // (K,32)
  const float* bary = (const float*)d_in[1];  // (K,5,8,3,2)
  const float* kern = (const float*)d_in[2];  // (5,8,5,8)
  const float* tw   = (const float*)d_in[3];  // (96,5,8,32)
  const float* sw   = (const float*)d_in[4];  // (96,1,32)
  const float* bias = (const float*)d_in[5];  // (96,)
  float* out = (float*)d_out;
  _Float16* Bp  = (_Float16*)d_ws;            // 2.02 MB
  _Float16* msh = (_Float16*)d_ws + BP_HALVES; // fp16 ms table, 6.4 MB

  hipLaunchKernelGGL(prep_B, dim3(48, 41), dim3(64), 0, stream, kern, tw, sw, Bp);
  hipLaunchKernelGGL(prep_msh, dim3((KPTS * 32 / 8 + 255) / 256), dim3(256), 0, stream,
                     ms, msh);
  hipLaunchKernelGGL(conv_main, dim3(1563), dim3(THREADS), 0, stream,
                     msh, bary, bias, Bp, out);
}

// Round 18
// 445.761 us; speedup vs baseline: 2.6439x; 1.0033x over previous
//
#include <hip/hip_runtime.h>
#include <hip/hip_bf16.h>
#include <stdint.h>

// ConvIntrinsic: fused  out[k,o,t] = relu( Σ_f sw[t,f]·ms[k,f]
//                + Σ_{x,y,f} W3[o,t,x,y,f]·interp0[k,x,y,f] + bias[t] )
// => GEMM (K=100000 × 1312) @ (1312 × 768), o=8 column duplicates o=0.
//
// R17: R16 fp16 champion (425 µs main dispatch) + prep fusion. The only
// addressable cost left is the ~22 µs prep/launch overhead: prep_msh and
// prep_B merged into one kernel (bodies byte-identical to R16's passing
// versions; block-uniform branch on blockIdx). conv_main untouched.
// 17-round model: per-window ~4090 cy = MFMA 930 + commit VALU 670 +
// ~2400 structural wait (falsified levers: barrier flavor, window count,
// occupancy+-traffic, kernel split, wave specialization, bf16 table).
// fp16 datapath = gather row -> 1 line + packed commit (the R16 -4.5%).

typedef __attribute__((ext_vector_type(8))) _Float16 half8;
typedef __attribute__((ext_vector_type(4))) _Float16 half4;
typedef __attribute__((ext_vector_type(4))) float floatx4;
typedef __attribute__((ext_vector_type(2))) float fx2;

#define KPTS 100000
#define OUT_STRIDE 864   // 9*96
#define BM 64
#define THREADS 512
#define BP_HALVES 1007616   // 41*48*64*8 (fp16 Bp element count)
#define MSH_BLOCKS 1563     // ceil(100000*32/8 / 256)
#define PB_BLOCKS 492       // 1968 (ntile,ch) pairs / 4 per block

// Workgroup barrier that does NOT drain vmcnt (champion form).
#define BARRIER() do {                              \
    __builtin_amdgcn_sched_barrier(0);              \
    asm volatile("s_waitcnt lgkmcnt(0)");           \
    __builtin_amdgcn_s_barrier();                   \
  } while (0)

// ---------------- fused prep: ms->fp16 table + B fragment pack ------------
// blocks [0, MSH_BLOCKS): convert ms to fp16 (8 elems/thread).
// blocks [MSH_BLOCKS, +PB_BLOCKS): 4 (ntile,ch) pairs per block, 64 lanes
// each: Bp[ch][ntile][lane][j] = B[ch*32 + (lane>>4)*8 + j][ntile*16 + (lane&15)]
__global__ __launch_bounds__(256) void prep_all(
    const float* __restrict__ ms,
    const float* __restrict__ kern,
    const float* __restrict__ tw,
    const float* __restrict__ sw,
    _Float16* __restrict__ Bp,
    _Float16* __restrict__ msh) {
  if (blockIdx.x < MSH_BLOCKS) {
    const int i = (blockIdx.x * 256 + threadIdx.x) * 8;
    if (i < KPTS * 32) {
      floatx4 a = *(const floatx4*)(ms + i);
      floatx4 b = *(const floatx4*)(ms + i + 4);
      half8 h;
#pragma unroll
      for (int j = 0; j < 4; ++j) {
        h[j] = (_Float16)a[j];
        h[4 + j] = (_Float16)b[j];
      }
      *reinterpret_cast<half8*>(msh + i) = h;
    }
    return;
  }
  const int w = (blockIdx.x - MSH_BLOCKS) * 4 + (threadIdx.x >> 6);
  if (w >= 1968) return;
  const int ch    = w / 48;         // 0..40
  const int ntile = w - ch * 48;    // 0..47
  const int lane  = threadIdx.x & 63;
  const int n = ntile * 16 + (lane & 15);
  const int o = n / 96;
  const int t = n - o * 96;
  const int fb = (lane >> 4) * 8;

  half8 v;
  if (ch < 40) {
    float kcol[40];
#pragma unroll
    for (int ra = 0; ra < 40; ++ra) kcol[ra] = kern[ra * 40 + ch];
#pragma unroll
    for (int j = 0; j < 8; ++j) {
      const int f = fb + j;
      float acc = 0.f;
      for (int r = 0; r < 5; ++r) {
#pragma unroll
        for (int a = 0; a < 8; ++a) {
          acc += kcol[r * 8 + a] * tw[((t * 5 + r) * 8 + ((a + o) & 7)) * 32 + f];
        }
      }
      v[j] = (_Float16)acc;
    }
  } else {
#pragma unroll
    for (int j = 0; j < 8; ++j) v[j] = (_Float16)sw[t * 32 + fb + j];
  }
  *reinterpret_cast<half8*>(Bp + ((size_t)(ch * 48 + ntile) * 64 + lane) * 8) = v;
}

// ---------------- main fused GEMM (R16-verbatim) --------------------------
__global__ __launch_bounds__(THREADS, 1) void conv_main(
    const _Float16* __restrict__ msh,
    const float* __restrict__ bary,
    const float* __restrict__ bias,
    const _Float16* __restrict__ Bp,
    float* __restrict__ out) {
  __shared__ _Float16 Atile[2][BM][40];   // 32 used halves + 8 pad (80 B stride)

  const int kbase = blockIdx.x * BM;
  const int tid = threadIdx.x;
  const int lane = tid & 63;
  const int wn = tid >> 6;             // 0..7  (wave n-group: cols wn*96)
  const int l15 = lane & 15;
  const int kh = lane >> 4;            // 0..3

  // A-build role: 8 threads per row, 4 fp16 f-columns each (8 B loads)
  const int arow = tid >> 3;           // 0..63
  const int af0 = (tid & 7) * 4;       // 0,4,...,28 (half index)
  const int krow = kbase + arow;
  const bool rowok = krow < KPTS;
  const float* __restrict__ brow = bary + (size_t)(rowok ? krow : 0) * 240;
  const _Float16* __restrict__ mrowh = msh + (size_t)(rowok ? krow : 0) * 32 + af0;

  // bary register sets (chunk parity): loaded 1 iter before use
  fx2 bE0, bE1, bE2, bO0, bO1, bO2;
  // gather register sets (chunk parity): issued 1 full iter before commit
  half4 eG0, eG1, eG2, oG0, oG1, oG2;
  float eW0, eW1, eW2, oW0, oW1, oW2;

  auto ldbary = [&](int c, fx2& p0, fx2& p1, fx2& p2) {
    if (rowok) {
      const fx2* bp = (const fx2*)(brow + c * 6);
      p0 = __builtin_nontemporal_load(bp);
      p1 = __builtin_nontemporal_load(bp + 1);
      p2 = __builtin_nontemporal_load(bp + 2);
    } else {
      p0 = (fx2)0.f; p1 = (fx2)0.f; p2 = (fx2)0.f;
    }
  };
  auto issueG = [&](int c, const fx2& p0, const fx2& p1, const fx2& p2,
                    half4& A, half4& B, half4& C,
                    float& W0, float& W1, float& W2) {
    if (c == 40) {   // center chunk: A[k][1280+f] = ms[k][f] (pass-through)
      A = *(const half4*)(mrowh);
      B = (half4)(_Float16)0.f; C = B;
      W0 = rowok ? 1.f : 0.f; W1 = 0.f; W2 = 0.f;
    } else {
      A = *(const half4*)(msh + ((size_t)(int)p0.x) * 32 + af0);
      B = *(const half4*)(msh + ((size_t)(int)p1.x) * 32 + af0);
      C = *(const half4*)(msh + ((size_t)(int)p2.x) * 32 + af0);
      W0 = p0.y; W1 = p1.y; W2 = p2.y;
    }
  };
  auto commitG = [&](const half4& A, const half4& B, const half4& C,
                     float W0, float W1, float W2, int buf) {
    const _Float16 w0 = (_Float16)W0, w1 = (_Float16)W1, w2 = (_Float16)W2;
    half4 s = A * w0;                  // v_pk_fma_f16 pairs
    s += B * w1;
    s += C * w2;
    *reinterpret_cast<half4*>(&Atile[buf][arow][af0]) = s;
  };

  half8 bfA[6], bfB[6];
  auto loadB = [&](int c, half8* dst) {
    const _Float16* bp = Bp + ((size_t)(c * 48 + wn * 6) * 64 + lane) * 8;
#pragma unroll
    for (int j = 0; j < 6; ++j)
      dst[j] = *reinterpret_cast<const half8*>(bp + (size_t)j * 512);
  };

  floatx4 acc[4][6];
#pragma unroll
  for (int mi = 0; mi < 4; ++mi)
#pragma unroll
    for (int nj = 0; nj < 6; ++nj) acc[mi][nj] = (floatx4)0.f;

  // ---- prologue ----
  {
    fx2 t0, t1, t2;
    ldbary(0, t0, t1, t2);
    issueG(0, t0, t1, t2, eG0, eG1, eG2, eW0, eW1, eW2);
    ldbary(1, t0, t1, t2);
    issueG(1, t0, t1, t2, oG0, oG1, oG2, oW0, oW1, oW2);
  }
  ldbary(2, bE0, bE1, bE2);           // for issue(2) at iter 0
  commitG(eG0, eG1, eG2, eW0, eW1, eW2, 0);   // chunk 0 -> Atile[0]
  loadB(0, bfA);
  BARRIER();

  // iter ch: issue(ch+2) with bary set (ch&1); ldbary(ch+3) -> other set;
  // MFMA chunk ch from Atile[ch&1] with B-set BF; loadB(ch+1) -> NBF;
  // commit(ch+1) -> Atile[(ch&1)^1]; barrier (global loads stay in flight).
#define ITER(ch, UB0, UB1, UB2, FB0, FB1, FB2,                                  \
             FG0, FG1, FG2, FW0, FW1, FW2,                                      \
             CG0, CG1, CG2, CW0, CW1, CW2, CUR, BF, NBF)                        \
  {                                                                             \
    if ((ch) + 2 <= 40)                                                         \
      issueG((ch) + 2, UB0, UB1, UB2, FG0, FG1, FG2, FW0, FW1, FW2);            \
    if ((ch) + 3 <= 39) ldbary((ch) + 3, FB0, FB1, FB2);                        \
    half8 af[4];                                                                \
    _Pragma("unroll")                                                           \
    for (int mi = 0; mi < 4; ++mi)                                              \
      af[mi] = *reinterpret_cast<const half8*>(&Atile[CUR][mi * 16 + l15][kh * 8]); \
    if ((ch) + 1 <= 40) loadB((ch) + 1, NBF);                                   \
    _Pragma("unroll")                                                           \
    for (int nj = 0; nj < 6; ++nj)                                              \
      _Pragma("unroll")                                                         \
      for (int mi = 0; mi < 4; ++mi)                                            \
        acc[mi][nj] = __builtin_amdgcn_mfma_f32_16x16x32_f16(af[mi], BF[nj],    \
                                                             acc[mi][nj], 0, 0, 0); \
    if ((ch) + 1 <= 40)                                                         \
      commitG(CG0, CG1, CG2, CW0, CW1, CW2, (CUR) ^ 1);                         \
    BARRIER();                                                                  \
  }

  for (int ch = 0; ch < 40; ch += 2) {
    // even iter: use bE, fill bO; fill E gathers, commit O gathers; Atile[0]; B=bfA
    ITER(ch,     bE0, bE1, bE2, bO0, bO1, bO2,
         eG0, eG1, eG2, eW0, eW1, eW2,
         oG0, oG1, oG2, oW0, oW1, oW2, 0, bfA, bfB)
    // odd iter: use bO, fill bE; fill O gathers, commit E gathers; Atile[1]; B=bfB
    ITER(ch + 1, bO0, bO1, bO2, bE0, bE1, bE2,
         oG0, oG1, oG2, oW0, oW1, oW2,
         eG0, eG1, eG2, eW0, eW1, eW2, 1, bfB, bfA)
  }
  ITER(40, bE0, bE1, bE2, bO0, bO1, bO2,
       eG0, eG1, eG2, eW0, eW1, eW2,
       oG0, oG1, oG2, oW0, oW1, oW2, 0, bfA, bfB)
#undef ITER

  // epilogue: bias + relu; out[k,o,t] = out[k*864 + n]; o=8 duplicates o=0
#pragma unroll
  for (int mi = 0; mi < 4; ++mi) {
    const int rb = kbase + mi * 16 + kh * 4;
#pragma unroll
    for (int nj = 0; nj < 6; ++nj) {
      const int n = wn * 96 + nj * 16 + l15;
      const float bsv = bias[nj * 16 + l15];
      const bool dup = (wn == 0);
#pragma unroll
      for (int i = 0; i < 4; ++i) {
        const int r = rb + i;
        if (r < KPTS) {
          float vv = fmaxf(acc[mi][nj][i] + bsv, 0.f);
          out[(size_t)r * OUT_STRIDE + n] = vv;
          if (dup) out[(size_t)r * OUT_STRIDE + 768 + n] = vv;
        }
      }
    }
  }
}

extern "C" void kernel_launch(void* const* d_in, const int* in_sizes, int n_in,
                              void* d_out, int out_size, void* d_ws, size_t ws_size,
                              hipStream_t stream) {
  const float* ms   = (const float*)d_in[0];  // (K,32)
  const float* bary = (const float*)d_in[1];  // (K,5,8,3,2)
  const float* kern = (const float*)d_in[2];  // (5,8,5,8)
  const float* tw   = (const float*)d_in[3];  // (96,5,8,32)
  const float* sw   = (const float*)d_in[4];  // (96,1,32)
  const float* bias = (const float*)d_in[5];  // (96,)
  float* out = (float*)d_out;
  _Float16* Bp  = (_Float16*)d_ws;             // 2.02 MB
  _Float16* msh = (_Float16*)d_ws + BP_HALVES; // fp16 ms table, 6.4 MB

  hipLaunchKernelGGL(prep_all, dim3(MSH_BLOCKS + PB_BLOCKS), dim3(256), 0, stream,
                     ms, kern, tw, sw, Bp, msh);
  hipLaunchKernelGGL(conv_main, dim3(1563), dim3(THREADS), 0, stream,
                     msh, bary, bias, Bp, out);
}

// Round 19
// 445.278 us; speedup vs baseline: 2.6468x; 1.0011x over previous
//
#include <hip/hip_runtime.h>
#include <hip/hip_bf16.h>
#include <stdint.h>

// ConvIntrinsic: fused  out[k,o,t] = relu( Σ_f sw[t,f]·ms[k,f]
//                + Σ_{x,y,f} W3[o,t,x,y,f]·interp0[k,x,y,f] + bias[t] )
// => GEMM (K=100000 × 1312) @ (1312 × 768), o=8 column duplicates o=0.
//
// R18: R17 champion + commit/MFMA interleave. Window cost is the serial
// sum of phases (MfmaUtil 20 + VALUBusy 16 = 36% combined issue, waves
// phase-locked). Split commitG into commit-COMPUTE (pk_fma interp, carries
// the gather vmcnt wait) placed BETWEEN the two 12-MFMA half-bursts, and
// commit-WRITE (ds_write) after. Same ops/deps; source order lets the
// scheduler hide the vmcnt wait + ~20 pk-VALU under MFMA group 2.
// Everything else R17-verbatim (fp16 datapath, fused prep, non-draining
// barrier, 2-ahead gather pipeline).

typedef __attribute__((ext_vector_type(8))) _Float16 half8;
typedef __attribute__((ext_vector_type(4))) _Float16 half4;
typedef __attribute__((ext_vector_type(4))) float floatx4;
typedef __attribute__((ext_vector_type(2))) float fx2;

#define KPTS 100000
#define OUT_STRIDE 864   // 9*96
#define BM 64
#define THREADS 512
#define BP_HALVES 1007616   // 41*48*64*8 (fp16 Bp element count)
#define MSH_BLOCKS 1563     // ceil(100000*32/8 / 256)
#define PB_BLOCKS 492       // 1968 (ntile,ch) pairs / 4 per block

// Workgroup barrier that does NOT drain vmcnt (champion form).
#define BARRIER() do {                              \
    __builtin_amdgcn_sched_barrier(0);              \
    asm volatile("s_waitcnt lgkmcnt(0)");           \
    __builtin_amdgcn_s_barrier();                   \
  } while (0)

// ---------------- fused prep: ms->fp16 table + B fragment pack ------------
__global__ __launch_bounds__(256) void prep_all(
    const float* __restrict__ ms,
    const float* __restrict__ kern,
    const float* __restrict__ tw,
    const float* __restrict__ sw,
    _Float16* __restrict__ Bp,
    _Float16* __restrict__ msh) {
  if (blockIdx.x < MSH_BLOCKS) {
    const int i = (blockIdx.x * 256 + threadIdx.x) * 8;
    if (i < KPTS * 32) {
      floatx4 a = *(const floatx4*)(ms + i);
      floatx4 b = *(const floatx4*)(ms + i + 4);
      half8 h;
#pragma unroll
      for (int j = 0; j < 4; ++j) {
        h[j] = (_Float16)a[j];
        h[4 + j] = (_Float16)b[j];
      }
      *reinterpret_cast<half8*>(msh + i) = h;
    }
    return;
  }
  const int w = (blockIdx.x - MSH_BLOCKS) * 4 + (threadIdx.x >> 6);
  if (w >= 1968) return;
  const int ch    = w / 48;         // 0..40
  const int ntile = w - ch * 48;    // 0..47
  const int lane  = threadIdx.x & 63;
  const int n = ntile * 16 + (lane & 15);
  const int o = n / 96;
  const int t = n - o * 96;
  const int fb = (lane >> 4) * 8;

  half8 v;
  if (ch < 40) {
    float kcol[40];
#pragma unroll
    for (int ra = 0; ra < 40; ++ra) kcol[ra] = kern[ra * 40 + ch];
#pragma unroll
    for (int j = 0; j < 8; ++j) {
      const int f = fb + j;
      float acc = 0.f;
      for (int r = 0; r < 5; ++r) {
#pragma unroll
        for (int a = 0; a < 8; ++a) {
          acc += kcol[r * 8 + a] * tw[((t * 5 + r) * 8 + ((a + o) & 7)) * 32 + f];
        }
      }
      v[j] = (_Float16)acc;
    }
  } else {
#pragma unroll
    for (int j = 0; j < 8; ++j) v[j] = (_Float16)sw[t * 32 + fb + j];
  }
  *reinterpret_cast<half8*>(Bp + ((size_t)(ch * 48 + ntile) * 64 + lane) * 8) = v;
}

// ---------------- main fused GEMM ----------------------------------------
__global__ __launch_bounds__(THREADS, 1) void conv_main(
    const _Float16* __restrict__ msh,
    const float* __restrict__ bary,
    const float* __restrict__ bias,
    const _Float16* __restrict__ Bp,
    float* __restrict__ out) {
  __shared__ _Float16 Atile[2][BM][40];   // 32 used halves + 8 pad (80 B stride)

  const int kbase = blockIdx.x * BM;
  const int tid = threadIdx.x;
  const int lane = tid & 63;
  const int wn = tid >> 6;             // 0..7  (wave n-group: cols wn*96)
  const int l15 = lane & 15;
  const int kh = lane >> 4;            // 0..3

  // A-build role: 8 threads per row, 4 fp16 f-columns each (8 B loads)
  const int arow = tid >> 3;           // 0..63
  const int af0 = (tid & 7) * 4;       // 0,4,...,28 (half index)
  const int krow = kbase + arow;
  const bool rowok = krow < KPTS;
  const float* __restrict__ brow = bary + (size_t)(rowok ? krow : 0) * 240;
  const _Float16* __restrict__ mrowh = msh + (size_t)(rowok ? krow : 0) * 32 + af0;

  // bary register sets (chunk parity): loaded 1 iter before use
  fx2 bE0, bE1, bE2, bO0, bO1, bO2;
  // gather register sets (chunk parity): issued 1 full iter before commit
  half4 eG0, eG1, eG2, oG0, oG1, oG2;
  float eW0, eW1, eW2, oW0, oW1, oW2;

  auto ldbary = [&](int c, fx2& p0, fx2& p1, fx2& p2) {
    if (rowok) {
      const fx2* bp = (const fx2*)(brow + c * 6);
      p0 = __builtin_nontemporal_load(bp);
      p1 = __builtin_nontemporal_load(bp + 1);
      p2 = __builtin_nontemporal_load(bp + 2);
    } else {
      p0 = (fx2)0.f; p1 = (fx2)0.f; p2 = (fx2)0.f;
    }
  };
  auto issueG = [&](int c, const fx2& p0, const fx2& p1, const fx2& p2,
                    half4& A, half4& B, half4& C,
                    float& W0, float& W1, float& W2) {
    if (c == 40) {   // center chunk: A[k][1280+f] = ms[k][f] (pass-through)
      A = *(const half4*)(mrowh);
      B = (half4)(_Float16)0.f; C = B;
      W0 = rowok ? 1.f : 0.f; W1 = 0.f; W2 = 0.f;
    } else {
      A = *(const half4*)(msh + ((size_t)(int)p0.x) * 32 + af0);
      B = *(const half4*)(msh + ((size_t)(int)p1.x) * 32 + af0);
      C = *(const half4*)(msh + ((size_t)(int)p2.x) * 32 + af0);
      W0 = p0.y; W1 = p1.y; W2 = p2.y;
    }
  };
  // commit split: COMPUTE (pk_fma interp; carries the gather vmcnt wait)
  auto commitCompute = [&](const half4& A, const half4& B, const half4& C,
                           float W0, float W1, float W2) -> half4 {
    const _Float16 w0 = (_Float16)W0, w1 = (_Float16)W1, w2 = (_Float16)W2;
    half4 s = A * w0;                  // v_pk_fma_f16 pairs
    s += B * w1;
    s += C * w2;
    return s;
  };
  auto commitWrite = [&](half4 s, int buf) {
    *reinterpret_cast<half4*>(&Atile[buf][arow][af0]) = s;
  };

  half8 bfA[6], bfB[6];
  auto loadB = [&](int c, half8* dst) {
    const _Float16* bp = Bp + ((size_t)(c * 48 + wn * 6) * 64 + lane) * 8;
#pragma unroll
    for (int j = 0; j < 6; ++j)
      dst[j] = *reinterpret_cast<const half8*>(bp + (size_t)j * 512);
  };

  floatx4 acc[4][6];
#pragma unroll
  for (int mi = 0; mi < 4; ++mi)
#pragma unroll
    for (int nj = 0; nj < 6; ++nj) acc[mi][nj] = (floatx4)0.f;

  // ---- prologue ----
  {
    fx2 t0, t1, t2;
    ldbary(0, t0, t1, t2);
    issueG(0, t0, t1, t2, eG0, eG1, eG2, eW0, eW1, eW2);
    ldbary(1, t0, t1, t2);
    issueG(1, t0, t1, t2, oG0, oG1, oG2, oW0, oW1, oW2);
  }
  ldbary(2, bE0, bE1, bE2);           // for issue(2) at iter 0
  commitWrite(commitCompute(eG0, eG1, eG2, eW0, eW1, eW2), 0);  // chunk 0 -> Atile[0]
  loadB(0, bfA);
  BARRIER();

  // iter ch: issue(ch+2); ldbary(ch+3); ds_read af; loadB(ch+1) -> NBF;
  // MFMA nj 0-2; commit-COMPUTE(ch+1) [vmcnt wait mid-burst]; MFMA nj 3-5;
  // commit-WRITE -> Atile[(ch&1)^1]; barrier (global loads stay in flight).
#define ITER(ch, UB0, UB1, UB2, FB0, FB1, FB2,                                  \
             FG0, FG1, FG2, FW0, FW1, FW2,                                      \
             CG0, CG1, CG2, CW0, CW1, CW2, CUR, BF, NBF)                        \
  {                                                                             \
    if ((ch) + 2 <= 40)                                                         \
      issueG((ch) + 2, UB0, UB1, UB2, FG0, FG1, FG2, FW0, FW1, FW2);            \
    if ((ch) + 3 <= 39) ldbary((ch) + 3, FB0, FB1, FB2);                        \
    half8 af[4];                                                                \
    _Pragma("unroll")                                                           \
    for (int mi = 0; mi < 4; ++mi)                                              \
      af[mi] = *reinterpret_cast<const half8*>(&Atile[CUR][mi * 16 + l15][kh * 8]); \
    if ((ch) + 1 <= 40) loadB((ch) + 1, NBF);                                   \
    _Pragma("unroll")                                                           \
    for (int nj = 0; nj < 3; ++nj)                                              \
      _Pragma("unroll")                                                         \
      for (int mi = 0; mi < 4; ++mi)                                            \
        acc[mi][nj] = __builtin_amdgcn_mfma_f32_16x16x32_f16(af[mi], BF[nj],    \
                                                             acc[mi][nj], 0, 0, 0); \
    half4 cs = (half4)(_Float16)0.f;                                            \
    if ((ch) + 1 <= 40)                                                         \
      cs = commitCompute(CG0, CG1, CG2, CW0, CW1, CW2);                         \
    _Pragma("unroll")                                                           \
    for (int nj = 3; nj < 6; ++nj)                                              \
      _Pragma("unroll")                                                         \
      for (int mi = 0; mi < 4; ++mi)                                            \
        acc[mi][nj] = __builtin_amdgcn_mfma_f32_16x16x32_f16(af[mi], BF[nj],    \
                                                             acc[mi][nj], 0, 0, 0); \
    if ((ch) + 1 <= 40)                                                         \
      commitWrite(cs, (CUR) ^ 1);                                               \
    BARRIER();                                                                  \
  }

  for (int ch = 0; ch < 40; ch += 2) {
    // even iter: use bE, fill bO; fill E gathers, commit O gathers; Atile[0]; B=bfA
    ITER(ch,     bE0, bE1, bE2, bO0, bO1, bO2,
         eG0, eG1, eG2, eW0, eW1, eW2,
         oG0, oG1, oG2, oW0, oW1, oW2, 0, bfA, bfB)
    // odd iter: use bO, fill bE; fill O gathers, commit E gathers; Atile[1]; B=bfB
    ITER(ch + 1, bO0, bO1, bO2, bE0, bE1, bE2,
         oG0, oG1, oG2, oW0, oW1, oW2,
         eG0, eG1, eG2, eW0, eW1, eW2, 1, bfB, bfA)
  }
  ITER(40, bE0, bE1, bE2, bO0, bO1, bO2,
       eG0, eG1, eG2, eW0, eW1, eW2,
       oG0, oG1, oG2, oW0, oW1, oW2, 0, bfA, bfB)
#undef ITER

  // epilogue: bias + relu; out[k,o,t] = out[k*864 + n]; o=8 duplicates o=0
#pragma unroll
  for (int mi = 0; mi < 4; ++mi) {
    const int rb = kbase + mi * 16 + kh * 4;
#pragma unroll
    for (int nj = 0; nj < 6; ++nj) {
      const int n = wn * 96 + nj * 16 + l15;
      const float bsv = bias[nj * 16 + l15];
      const bool dup = (wn == 0);
#pragma unroll
      for (int i = 0; i < 4; ++i) {
        const int r = rb + i;
        if (r < KPTS) {
          float vv = fmaxf(acc[mi][nj][i] + bsv, 0.f);
          out[(size_t)r * OUT_STRIDE + n] = vv;
          if (dup) out[(size_t)r * OUT_STRIDE + 768 + n] = vv;
        }
      }
    }
  }
}

extern "C" void kernel_launch(void* const* d_in, const int* in_sizes, int n_in,
                              void* d_out, int out_size, void* d_ws, size_t ws_size,
                              hipStream_t stream) {
  const float* ms   = (const float*)d_in[0];  // (K,32)
  const float* bary = (const float*)d_in[1];  // (K,5,8,3,2)
  const float* kern = (const float*)d_in[2];  // (5,8,5,8)
  const float* tw   = (const float*)d_in[3];  // (96,5,8,32)
  const float* sw   = (const float*)d_in[4];  // (96,1,32)
  const float* bias = (const float*)d_in[5];  // (96,)
  float* out = (float*)d_out;
  _Float16* Bp  = (_Float16*)d_ws;             // 2.02 MB
  _Float16* msh = (_Float16*)d_ws + BP_HALVES; // fp16 ms table, 6.4 MB

  hipLaunchKernelGGL(prep_all, dim3(MSH_BLOCKS + PB_BLOCKS), dim3(256), 0, stream,
                     ms, kern, tw, sw, Bp, msh);
  hipLaunchKernelGGL(conv_main, dim3(1563), dim3(THREADS), 0, stream,
                     msh, bary, bias, Bp, out);
}